// Round 6
// baseline (463.743 us; speedup 1.0000x reference)
//
#include <hip/hip_runtime.h>
#include <hip/hip_bf16.h>
#include <math.h>

#define S_LEN 2048
#define NHEAD 16
#define DHEAD 64
#define DMODEL 1024
#define NBATCH 2

typedef unsigned short u16;
typedef __attribute__((ext_vector_type(8))) short bf16x8;
typedef __attribute__((ext_vector_type(4))) short short4v;
typedef __attribute__((ext_vector_type(4))) float f32x4;

__device__ __forceinline__ short f2bs(float x) {
    __hip_bfloat16 h = __float2bfloat16(x);
    return __builtin_bit_cast(short, h);
}

#define GL2LDS(g, l)                                                         \
    __builtin_amdgcn_global_load_lds(                                        \
        (const __attribute__((address_space(1))) void*)(g),                  \
        (__attribute__((address_space(3))) void*)(l), 16, 0, 0)

// ---------------------------------------------------------------------------
// fp32 -> bf16 flat cast. grid = n/1024.
// ---------------------------------------------------------------------------
__global__ __launch_bounds__(256) void cast_f32_bf16(const float* __restrict__ in,
                                                     u16* __restrict__ out) {
    const int i = (blockIdx.x * 256 + threadIdx.x) * 4;
    float4 v = *(const float4*)(in + i);
    short4v t;
    t[0] = f2bs(v.x); t[1] = f2bs(v.y); t[2] = f2bs(v.z); t[3] = f2bs(v.w);
    *(short4v*)(out + i) = t;
}

// ---------------------------------------------------------------------------
// W [K][N] fp32 -> Wt [N][K] bf16 (transpose + cast). grid = (N/64, K/64)
// ---------------------------------------------------------------------------
__global__ __launch_bounds__(256) void transp_cast(const float* __restrict__ W,
                                                   u16* __restrict__ Wt,
                                                   int K, int N) {
    __shared__ float t[64][65];
    const int k0 = blockIdx.y * 64, n0 = blockIdx.x * 64;
    const int r = threadIdx.x >> 4;
    const int c4 = (threadIdx.x & 15) * 4;
    #pragma unroll
    for (int it = 0; it < 4; ++it) {
        float4 v = *(const float4*)(W + (size_t)(k0 + it * 16 + r) * N + n0 + c4);
        t[c4 + 0][it * 16 + r] = v.x;
        t[c4 + 1][it * 16 + r] = v.y;
        t[c4 + 2][it * 16 + r] = v.z;
        t[c4 + 3][it * 16 + r] = v.w;
    }
    __syncthreads();
    #pragma unroll
    for (int it = 0; it < 4; ++it) {
        const int nn = it * 16 + r;
        short4v o;
        o[0] = f2bs(t[nn][c4 + 0]); o[1] = f2bs(t[nn][c4 + 1]);
        o[2] = f2bs(t[nn][c4 + 2]); o[3] = f2bs(t[nn][c4 + 3]);
        *(short4v*)(Wt + (size_t)(n0 + nn) * K + k0 + c4) = o;
    }
}

// ---------------------------------------------------------------------------
// Shared GEMM main-loop macro: 128x128 tile, BK=64, XOR-swizzled LDS,
// global_load_lds width-16. Leaves acc[4][4] (f32x4) computed.
// ---------------------------------------------------------------------------
#define GEMM_BODY(Aptr, Btptr, Kdim)                                          \
    __shared__ u16 As[128 * 64];                                              \
    __shared__ u16 Bs[128 * 64];                                              \
    const int tid = threadIdx.x;                                              \
    const int lane = tid & 63;                                                \
    const int w = tid >> 6;                                                   \
    const int quad = lane >> 4, col = lane & 15;                              \
    const int bm = blockIdx.y * 128, bn = blockIdx.x * 128;                   \
    const int wm = (w >> 1) * 64, wn = (w & 1) * 64;                          \
    f32x4 acc[4][4];                                                          \
    _Pragma("unroll")                                                         \
    for (int mt = 0; mt < 4; ++mt)                                            \
        _Pragma("unroll")                                                     \
        for (int nt = 0; nt < 4; ++nt) acc[mt][nt] = (f32x4){0.f,0.f,0.f,0.f};\
    for (int k0 = 0; k0 < (Kdim); k0 += 64) {                                 \
        _Pragma("unroll")                                                     \
        for (int it = 0; it < 4; ++it) {                                      \
            const int cb = it * 256 + w * 64;                                 \
            const int c = cb + lane;                                          \
            const int r = c >> 3;                                             \
            const int o = ((c & 7) ^ (r & 7)) * 8;                            \
            GL2LDS((Aptr) + (size_t)(bm + r) * (Kdim) + k0 + o, As + (size_t)cb * 8); \
            GL2LDS((Btptr) + (size_t)(bn + r) * (Kdim) + k0 + o, Bs + (size_t)cb * 8);\
        }                                                                     \
        __syncthreads();                                                      \
        _Pragma("unroll")                                                     \
        for (int kc = 0; kc < 2; ++kc) {                                      \
            bf16x8 af[4], bfr[4];                                             \
            _Pragma("unroll")                                                 \
            for (int t = 0; t < 4; ++t) {                                     \
                const int am = wm + t * 16 + col;                             \
                const int aj = kc * 4 + quad;                                 \
                af[t] = *(const bf16x8*)&As[(size_t)am * 64 + ((aj ^ (am & 7)) * 8)]; \
                const int bn2 = wn + t * 16 + col;                            \
                bfr[t] = *(const bf16x8*)&Bs[(size_t)bn2 * 64 + ((aj ^ (bn2 & 7)) * 8)]; \
            }                                                                 \
            _Pragma("unroll")                                                 \
            for (int mt = 0; mt < 4; ++mt)                                    \
                _Pragma("unroll")                                             \
                for (int nt = 0; nt < 4; ++nt)                                \
                    acc[mt][nt] = __builtin_amdgcn_mfma_f32_16x16x32_bf16(    \
                        af[mt], bfr[nt], acc[mt][nt], 0, 0, 0);               \
        }                                                                     \
        __syncthreads();                                                      \
    }

// ---------------------------------------------------------------------------
// qkv GEMM with fused head-major scatter epilogue (+q biases).
// ---------------------------------------------------------------------------
__global__ __launch_bounds__(256, 2) void gemm_qkv(
    const u16* __restrict__ A, const u16* __restrict__ Bt,
    const float* __restrict__ rwb, const float* __restrict__ rrb,
    u16* __restrict__ qrw_b, u16* __restrict__ qrr_b,
    u16* __restrict__ kb, u16* __restrict__ vbT)
{
    GEMM_BODY(A, Bt, DMODEL)
    #pragma unroll
    for (int mt = 0; mt < 4; ++mt) {
        const int row0 = bm + wm + mt * 16 + quad * 4;
        const int b = row0 >> 11;
        const int s0 = row0 & 2047;
        #pragma unroll
        for (int nt = 0; nt < 4; ++nt) {
            const int cn = bn + wn + nt * 16 + col;     // [0,3072)
            const int sec = cn >> 10;                   // wave-uniform per nt
            const int cc = cn & 1023;
            const int h = cc >> 6, d = cc & 63;
            const int bh = b * NHEAD + h;
            if (sec == 0) {
                const float bw = rwb[cc], br = rrb[cc];
                #pragma unroll
                for (int r = 0; r < 4; ++r) {
                    const size_t o = ((size_t)bh * S_LEN + s0 + r) * 64 + d;
                    qrw_b[o] = (u16)f2bs(acc[mt][nt][r] + bw);
                    qrr_b[o] = (u16)f2bs(acc[mt][nt][r] + br);
                }
            } else if (sec == 1) {
                #pragma unroll
                for (int r = 0; r < 4; ++r)
                    kb[((size_t)bh * S_LEN + s0 + r) * 64 + d] =
                        (u16)f2bs(acc[mt][nt][r]);
            } else {
                short4v t;
                t[0] = f2bs(acc[mt][nt][0]); t[1] = f2bs(acc[mt][nt][1]);
                t[2] = f2bs(acc[mt][nt][2]); t[3] = f2bs(acc[mt][nt][3]);
                *(short4v*)(vbT + ((size_t)bh * 64 + d) * S_LEN + s0) = t;
            }
        }
    }
}

// ---------------------------------------------------------------------------
// rel GEMM with fused head-major scatter: rkb [NHEAD][S][64].
// ---------------------------------------------------------------------------
__global__ __launch_bounds__(256, 2) void gemm_rel(
    const u16* __restrict__ A, const u16* __restrict__ Bt,
    u16* __restrict__ rkb)
{
    GEMM_BODY(A, Bt, DMODEL)
    #pragma unroll
    for (int mt = 0; mt < 4; ++mt) {
        const int l0 = bm + wm + mt * 16 + quad * 4;
        #pragma unroll
        for (int nt = 0; nt < 4; ++nt) {
            const int cn = bn + wn + nt * 16 + col;
            const int h = cn >> 6, d = cn & 63;
            #pragma unroll
            for (int r = 0; r < 4; ++r)
                rkb[((size_t)h * S_LEN + l0 + r) * 64 + d] =
                    (u16)f2bs(acc[mt][nt][r]);
        }
    }
}

// ---------------------------------------------------------------------------
// Generic bf16 GEMM, fp32 output: C = A @ Bt^T (out-projection).
// ---------------------------------------------------------------------------
__global__ __launch_bounds__(256, 2) void gemm_out(
    const u16* __restrict__ A, const u16* __restrict__ Bt,
    float* __restrict__ Cf, int N, int K)
{
    GEMM_BODY(A, Bt, K)
    #pragma unroll
    for (int mt = 0; mt < 4; ++mt)
        #pragma unroll
        for (int nt = 0; nt < 4; ++nt)
            #pragma unroll
            for (int r = 0; r < 4; ++r) {
                const int row = bm + wm + mt * 16 + quad * 4 + r;
                const int cn = bn + wn + nt * 16 + col;
                Cf[(size_t)row * N + cn] = acc[mt][nt][r];
            }
}

// ---------------------------------------------------------------------------
// MFMA bf16 flash attention v5: Q-tile 128, 8 waves. LDS-pipe diet vs v4:
//  - V read direct global->VGPR (VMEM pipe), Vs staging removed
//  - diagonal extraction: rotate 5 groups once per r (20 bpermutes, was 32)
// K + rk panel stay LDS-staged (block-shared). Analytic rel-shift unchanged.
// ---------------------------------------------------------------------------
__global__ __launch_bounds__(512, 2) void flash_attn(
    const u16* __restrict__ qrw_b, const u16* __restrict__ qrr_b,
    const u16* __restrict__ kb, const u16* __restrict__ vbT,
    const u16* __restrict__ rkb, const int* __restrict__ mask,
    u16* __restrict__ ctxb)
{
    const int lane = threadIdx.x & 63;
    const int w    = threadIdx.x >> 6;      // 0..7
    const int quad = lane >> 4;
    const int col  = lane & 15;
    const int bh   = blockIdx.y;
    const int b    = bh >> 4;
    const int n    = bh & 15;
    const int B0   = blockIdx.x * 128;
    const int iw0  = B0 + w * 16;

    __shared__ u16 Ks[64 * 64];      // XOR-swizzled
    __shared__ u16 Rs[192 * 64];     // rk panel
    __shared__ u16 Pr[8][16][72];
    __shared__ float madd[S_LEN];

    const size_t headQ = (size_t)bh * S_LEN * 64;
    const size_t headR = (size_t)n  * S_LEN * 64;

    for (int i = threadIdx.x; i < S_LEN; i += 512)
        madd[i] = mask[b * S_LEN + i] ? -16384.f : 0.f;

    bf16x8 a_rw[2], a_rr0[2], a_rr1[2];
    {
        const int r0 = iw0 + col;
        const int r1 = (r0 + 1 < S_LEN) ? (r0 + 1) : (S_LEN - 1);
        #pragma unroll
        for (int kc = 0; kc < 2; ++kc) {
            const int doff = kc * 32 + quad * 8;
            a_rw[kc]  = *(const bf16x8*)(qrw_b + headQ + (size_t)r0 * 64 + doff);
            a_rr0[kc] = *(const bf16x8*)(qrr_b + headQ + (size_t)r0 * 64 + doff);
            a_rr1[kc] = *(const bf16x8*)(qrr_b + headQ + (size_t)r1 * 64 + doff);
        }
    }

    f32x4 O[4];
    float l_acc[4] = {0.f, 0.f, 0.f, 0.f};
    #pragma unroll
    for (int dt = 0; dt < 4; ++dt) O[dt] = (f32x4){0.f, 0.f, 0.f, 0.f};

    const int swz  = ((lane & 7) ^ ((lane >> 3) & 7)) * 8;
    const int lrow = lane >> 3;
    const int csel = col & 7;

    for (int u0 = 0; u0 < S_LEN; u0 += 64) {
        const int dblk = B0 - u0;                 // block-uniform, mult of 64
        const int dw = dblk + 16 * w;             // wave-uniform
        const bool mixed = (dw >= 0) && (dw <= 48);
        __syncthreads();
        // ---- stage K (8 chunks), rk panel (24); 4 chunks/wave ----
        const int pbase = (dblk >= 0) ? (S_LEN - 128 - dblk) : (-dblk - 129);
        #pragma unroll
        for (int t = 0; t < 4; ++t) {
            const int idx = w * 4 + t;
            if (idx < 8) {
                GL2LDS(kb + headQ + (size_t)(u0 + idx * 8 + lrow) * 64 + swz,
                       Ks + idx * 512);
            } else {
                const int c = idx - 8;
                int rr = pbase + c * 8 + lrow;
                rr = rr < 0 ? 0 : (rr > S_LEN - 1 ? S_LEN - 1 : rr);
                GL2LDS(rkb + headR + (size_t)rr * 64 + swz, Rs + c * 512);
            }
        }
        // mixed waves: direct-VGPR loads of the other region
        bf16x8 rf2[5][2];
        if (mixed) {
            #pragma unroll
            for (int g = 0; g < 5; ++g) {
                const int u = g * 16 + col;
                int row = (dblk >= 0) ? (u - dw - 17) : (S_LEN - 16 - dw + u);
                row = row < 0 ? 0 : (row > S_LEN - 1 ? S_LEN - 1 : row);
                const u16* rb = rkb + headR + (size_t)row * 64 + quad * 8;
                rf2[g][0] = *(const bf16x8*)(rb);
                rf2[g][1] = *(const bf16x8*)(rb + 32);
            }
        }
        __syncthreads();

        // ---- ac = Qrw . K^T ----
        f32x4 sc[4];
        #pragma unroll
        for (int nt = 0; nt < 4; ++nt) {
            const int m = nt * 16 + col;
            bf16x8 k0 = *(const bf16x8*)&Ks[m * 64 + ((quad ^ csel) * 8)];
            bf16x8 k1 = *(const bf16x8*)&Ks[m * 64 + (((4 + quad) ^ csel) * 8)];
            f32x4 c = (f32x4){0.f, 0.f, 0.f, 0.f};
            c = __builtin_amdgcn_mfma_f32_16x16x32_bf16(a_rw[0], k0, c, 0, 0, 0);
            c = __builtin_amdgcn_mfma_f32_16x16x32_bf16(a_rw[1], k1, c, 0, 0, 0);
            sc[nt] = c;
        }

        // ---- bd: panel GEMM (+ VGPR pass for mixed waves) ----
        f32x4 pnl[5], oth[5];
        {
            const bf16x8* aP = (dblk >= 0) ? a_rr0 : a_rr1;
            #pragma unroll
            for (int g = 0; g < 5; ++g) {
                const int m = g * 16 + col + 112 - 16 * w;   // m&7 == col&7
                bf16x8 r0 = *(const bf16x8*)&Rs[m * 64 + ((quad ^ csel) * 8)];
                bf16x8 r1 = *(const bf16x8*)&Rs[m * 64 + (((4 + quad) ^ csel) * 8)];
                f32x4 c = (f32x4){0.f, 0.f, 0.f, 0.f};
                c = __builtin_amdgcn_mfma_f32_16x16x32_bf16(aP[0], r0, c, 0, 0, 0);
                c = __builtin_amdgcn_mfma_f32_16x16x32_bf16(aP[1], r1, c, 0, 0, 0);
                pnl[g] = c;
            }
        }
        #pragma unroll
        for (int g = 0; g < 5; ++g) oth[g] = (f32x4){0.f, 0.f, 0.f, 0.f};
        if (mixed) {
            const bf16x8* aV = (dblk >= 0) ? a_rr1 : a_rr0;
            #pragma unroll
            for (int g = 0; g < 5; ++g) {
                f32x4 c = (f32x4){0.f, 0.f, 0.f, 0.f};
                c = __builtin_amdgcn_mfma_f32_16x16x32_bf16(aV[0], rf2[g][0], c, 0, 0, 0);
                c = __builtin_amdgcn_mfma_f32_16x16x32_bf16(aV[1], rf2[g][1], c, 0, 0, 0);
                oth[g] = c;
            }
        }
        // unified 3-way select into pnl[]
        const int lim1 = 15 + dw;
        #pragma unroll
        for (int g = 0; g < 5; ++g) {
            const int u = g * 16 + col;
            #pragma unroll
            for (int r = 0; r < 4; ++r) {
                const float r1v = (dblk >= 0) ? pnl[g][r] : oth[g][r];
                const float r2v = (dblk >= 0) ? oth[g][r] : pnl[g][r];
                pnl[g][r] = (u <= lim1) ? r1v : ((u == lim1 + 1) ? 0.f : r2v);
            }
        }

        // ---- V fragments: direct global (VMEM pipe, covered by VALU below)
        bf16x8 vf[4][2];
        #pragma unroll
        for (int dt = 0; dt < 4; ++dt) {
            const u16* vb = vbT + ((size_t)bh * 64 + dt * 16 + col) * S_LEN
                            + u0 + quad * 8;
            vf[dt][0] = *(const bf16x8*)(vb);
            vf[dt][1] = *(const bf16x8*)(vb + 32);
        }

        // ---- extract diagonal (rotate-once-per-r), exp, accumulate l ----
        float madd_v[4];
        #pragma unroll
        for (int nt = 0; nt < 4; ++nt)
            madd_v[nt] = madd[u0 + nt * 16 + col];
        #pragma unroll
        for (int r = 0; r < 4; ++r) {
            const int uo = col + 15 - quad * 4 - r;       // [0,30]
            const int src = (quad << 4) | (uo & 15);
            float rot[5];
            #pragma unroll
            for (int g = 0; g < 5; ++g)
                rot[g] = __shfl(pnl[g][r], src, 64);
            #pragma unroll
            for (int nt = 0; nt < 4; ++nt) {
                const float bd = (uo < 16) ? rot[nt] : rot[nt + 1];
                const float p = __expf(fmaf(sc[nt][r] + bd, 0.125f, madd_v[nt]));
                sc[nt][r] = p;
                l_acc[r] += p;
            }
        }

        // ---- P: C-layout -> LDS row-major -> A-frags ----
        #pragma unroll
        for (int nt = 0; nt < 4; ++nt)
            #pragma unroll
            for (int r = 0; r < 4; ++r)
                Pr[w][quad * 4 + r][nt * 16 + col] = (u16)f2bs(sc[nt][r]);
        bf16x8 pa[2];
        pa[0] = *(const bf16x8*)&Pr[w][col][quad * 8];
        pa[1] = *(const bf16x8*)&Pr[w][col][32 + quad * 8];

        // ---- O += P . V ----
        #pragma unroll
        for (int dt = 0; dt < 4; ++dt) {
            f32x4 c = O[dt];
            c = __builtin_amdgcn_mfma_f32_16x16x32_bf16(pa[0], vf[dt][0], c, 0, 0, 0);
            c = __builtin_amdgcn_mfma_f32_16x16x32_bf16(pa[1], vf[dt][1], c, 0, 0, 0);
            O[dt] = c;
        }
    }

    float inv[4];
    #pragma unroll
    for (int r = 0; r < 4; ++r) {
        float s = l_acc[r];
        #pragma unroll
        for (int off = 1; off < 16; off <<= 1)
            s += __shfl_xor(s, off, 64);
        inv[r] = 1.f / s;
    }
    #pragma unroll
    for (int dt = 0; dt < 4; ++dt)
        #pragma unroll
        for (int r = 0; r < 4; ++r) {
            const int i = iw0 + quad * 4 + r;
            ctxb[((size_t)b * S_LEN + i) * DMODEL + n * 64 + dt * 16 + col] =
                (u16)f2bs(O[dt][r] * inv[r]);
        }
}

// ---------------------------------------------------------------------------
// out = LayerNorm(x + attn_out)
// ---------------------------------------------------------------------------
__global__ __launch_bounds__(256) void ln_kernel(const float* __restrict__ x,
                                                 const float* __restrict__ ao,
                                                 const float* __restrict__ gamma,
                                                 const float* __restrict__ beta,
                                                 float* __restrict__ out) {
    const int r = blockIdx.x;
    const int tid = threadIdx.x;
    const size_t base = (size_t)r * DMODEL + tid * 4;
    float4 xv = *(const float4*)(x + base);
    float4 av = *(const float4*)(ao + base);
    float v0 = xv.x + av.x, v1 = xv.y + av.y, v2 = xv.z + av.z, v3 = xv.w + av.w;

    float s = v0 + v1 + v2 + v3;
    #pragma unroll
    for (int off = 32; off > 0; off >>= 1) s += __shfl_xor(s, off, 64);
    __shared__ float red[4];
    __shared__ float red2[4];
    if ((tid & 63) == 0) red[tid >> 6] = s;
    __syncthreads();
    float mu = (red[0] + red[1] + red[2] + red[3]) * (1.0f / DMODEL);

    float d0 = v0 - mu, d1 = v1 - mu, d2 = v2 - mu, d3 = v3 - mu;
    float q = d0 * d0 + d1 * d1 + d2 * d2 + d3 * d3;
    #pragma unroll
    for (int off = 32; off > 0; off >>= 1) q += __shfl_xor(q, off, 64);
    if ((tid & 63) == 0) red2[tid >> 6] = q;
    __syncthreads();
    float var = (red2[0] + red2[1] + red2[2] + red2[3]) * (1.0f / DMODEL);
    float rstd = rsqrtf(var + 1e-5f);

    float4 g  = *(const float4*)(gamma + tid * 4);
    float4 be = *(const float4*)(beta + tid * 4);
    float4 o = make_float4(d0 * rstd * g.x + be.x,
                           d1 * rstd * g.y + be.y,
                           d2 * rstd * g.z + be.z,
                           d3 * rstd * g.w + be.w);
    *(float4*)(out + base) = o;
}

// ---------------------------------------------------------------------------
extern "C" void kernel_launch(void* const* d_in, const int* in_sizes, int n_in,
                              void* d_out, int out_size, void* d_ws, size_t ws_size,
                              hipStream_t stream) {
    const float* x    = (const float*)d_in[0];
    const float* rpos = (const float*)d_in[1];
    const float* rwb  = (const float*)d_in[2];
    const float* rrb  = (const float*)d_in[3];
    const int*   mask = (const int*)  d_in[4];
    const float* Wqkv = (const float*)d_in[5];
    const float* Wrel = (const float*)d_in[6];
    const float* Wout = (const float*)d_in[7];
    const float* gam  = (const float*)d_in[8];
    const float* bet  = (const float*)d_in[9];
    float* out = (float*)d_out;

    // ---- workspace layout (u16 units), ~86 MB ----
    u16* wsb   = (u16*)d_ws;
    u16* ctxb  = wsb;                        // [4096][1024] bf16
    float* ao  = (float*)(wsb + 4194304);    // [4096][1024] f32
    u16* qrw_b = wsb + 12582912;             // [BH][S][64]
    u16* qrr_b = qrw_b + 4194304;
    u16* kb    = qrr_b + 4194304;
    u16* vbT   = kb + 4194304;               // [BH][64][S]
    u16* rkb   = vbT + 4194304;              // [NHEAD][S][64]
    u16* xb    = rkb + 2097152;              // [4096][1024]
    u16* rposb = xb + 4194304;               // [2048][1024]
    u16* Wqkvt = rposb + 2097152;            // [3072][1024]
    u16* Wrelt = Wqkvt + 3145728;            // [1024][1024]
    u16* Woutt = Wrelt + 1048576;            // [1024][1024]

    dim3 blk(256);
    cast_f32_bf16<<<dim3(4096), blk, 0, stream>>>(x, xb);
    transp_cast<<<dim3(48, 16), blk, 0, stream>>>(Wqkv, Wqkvt, DMODEL, 3 * DMODEL);
    gemm_qkv<<<dim3(24, 32), blk, 0, stream>>>(xb, Wqkvt, rwb, rrb,
                                               qrw_b, qrr_b, kb, vbT);
    cast_f32_bf16<<<dim3(2048), blk, 0, stream>>>(rpos, rposb);
    transp_cast<<<dim3(16, 16), blk, 0, stream>>>(Wrel, Wrelt, DMODEL, DMODEL);
    gemm_rel<<<dim3(8, 16), blk, 0, stream>>>(rposb, Wrelt, rkb);
    transp_cast<<<dim3(16, 16), blk, 0, stream>>>(Wout, Woutt, DMODEL, DMODEL);
    flash_attn<<<dim3(S_LEN / 128, NBATCH * NHEAD), dim3(512), 0, stream>>>(
        qrw_b, qrr_b, kb, vbT, rkb, mask, ctxb);
    gemm_out<<<dim3(8, 32), blk, 0, stream>>>(ctxb, Woutt, ao, DMODEL, DMODEL);
    ln_kernel<<<dim3(NBATCH * S_LEN), blk, 0, stream>>>(x, ao, gam, bet, out);
}

// Round 7
// 417.552 us; speedup vs baseline: 1.1106x; 1.1106x over previous
//
#include <hip/hip_runtime.h>
#include <hip/hip_bf16.h>
#include <math.h>

#define S_LEN 2048
#define NHEAD 16
#define DHEAD 64
#define DMODEL 1024
#define NBATCH 2

typedef unsigned short u16;
typedef __attribute__((ext_vector_type(8))) short bf16x8;
typedef __attribute__((ext_vector_type(4))) short short4v;
typedef __attribute__((ext_vector_type(4))) float f32x4;

__device__ __forceinline__ short f2bs(float x) {
    __hip_bfloat16 h = __float2bfloat16(x);
    return __builtin_bit_cast(short, h);
}

#define GL2LDS(g, l)                                                         \
    __builtin_amdgcn_global_load_lds(                                        \
        (const __attribute__((address_space(1))) void*)(g),                  \
        (__attribute__((address_space(3))) void*)(l), 16, 0, 0)

// ---------------------------------------------------------------------------
// fused fp32 -> bf16 casts: x (4096 blocks) then rpos (2048 blocks).
// ---------------------------------------------------------------------------
__global__ __launch_bounds__(256) void cast_all(const float* __restrict__ x,
                                                const float* __restrict__ rpos,
                                                u16* __restrict__ xb,
                                                u16* __restrict__ rposb) {
    int bid = blockIdx.x;
    const float* in;
    u16* out;
    if (bid < 4096) { in = x; out = xb; }
    else            { in = rpos; out = rposb; bid -= 4096; }
    const int i = (bid * 256 + threadIdx.x) * 4;
    float4 v = *(const float4*)(in + i);
    short4v t;
    t[0] = f2bs(v.x); t[1] = f2bs(v.y); t[2] = f2bs(v.z); t[3] = f2bs(v.w);
    *(short4v*)(out + i) = t;
}

// ---------------------------------------------------------------------------
// fused W [K][N] fp32 -> Wt [N][K] bf16 for Wqkv / Wrel / Wout.
// grid (80, 16): bx<48 -> Wqkv, <64 -> Wrel, else Wout. K=1024 for all.
// ---------------------------------------------------------------------------
__global__ __launch_bounds__(256) void transp_cast_all(
    const float* __restrict__ Wqkv, const float* __restrict__ Wrel,
    const float* __restrict__ Wout,
    u16* __restrict__ Wqkvt, u16* __restrict__ Wrelt, u16* __restrict__ Woutt)
{
    __shared__ float t[64][65];
    int bx = blockIdx.x;
    const float* W;
    u16* Wt;
    int N;
    if (bx < 48)      { W = Wqkv; Wt = Wqkvt; N = 3 * DMODEL; }
    else if (bx < 64) { W = Wrel; Wt = Wrelt; N = DMODEL; bx -= 48; }
    else              { W = Wout; Wt = Woutt; N = DMODEL; bx -= 64; }
    const int k0 = blockIdx.y * 64, n0 = bx * 64;
    const int r = threadIdx.x >> 4;
    const int c4 = (threadIdx.x & 15) * 4;
    #pragma unroll
    for (int it = 0; it < 4; ++it) {
        float4 v = *(const float4*)(W + (size_t)(k0 + it * 16 + r) * N + n0 + c4);
        t[c4 + 0][it * 16 + r] = v.x;
        t[c4 + 1][it * 16 + r] = v.y;
        t[c4 + 2][it * 16 + r] = v.z;
        t[c4 + 3][it * 16 + r] = v.w;
    }
    __syncthreads();
    #pragma unroll
    for (int it = 0; it < 4; ++it) {
        const int nn = it * 16 + r;
        short4v o;
        o[0] = f2bs(t[nn][c4 + 0]); o[1] = f2bs(t[nn][c4 + 1]);
        o[2] = f2bs(t[nn][c4 + 2]); o[3] = f2bs(t[nn][c4 + 3]);
        *(short4v*)(Wt + (size_t)(n0 + nn) * DMODEL + k0 + c4) = o;
    }
}

// ---------------------------------------------------------------------------
// Shared GEMM main-loop macro: 128x128 tile, BK=64, XOR-swizzled LDS,
// global_load_lds width-16. Leaves acc[4][4] (f32x4) computed.
// ---------------------------------------------------------------------------
#define GEMM_BODY(Aptr, Btptr, Kdim)                                          \
    __shared__ u16 As[128 * 64];                                              \
    __shared__ u16 Bs[128 * 64];                                              \
    const int tid = threadIdx.x;                                              \
    const int lane = tid & 63;                                                \
    const int w = tid >> 6;                                                   \
    const int quad = lane >> 4, col = lane & 15;                              \
    const int bm = blockIdx.y * 128, bn = blockIdx.x * 128;                   \
    const int wm = (w >> 1) * 64, wn = (w & 1) * 64;                          \
    f32x4 acc[4][4];                                                          \
    _Pragma("unroll")                                                         \
    for (int mt = 0; mt < 4; ++mt)                                            \
        _Pragma("unroll")                                                     \
        for (int nt = 0; nt < 4; ++nt) acc[mt][nt] = (f32x4){0.f,0.f,0.f,0.f};\
    for (int k0 = 0; k0 < (Kdim); k0 += 64) {                                 \
        _Pragma("unroll")                                                     \
        for (int it = 0; it < 4; ++it) {                                      \
            const int cb = it * 256 + w * 64;                                 \
            const int c = cb + lane;                                          \
            const int r = c >> 3;                                             \
            const int o = ((c & 7) ^ (r & 7)) * 8;                            \
            GL2LDS((Aptr) + (size_t)(bm + r) * (Kdim) + k0 + o, As + (size_t)cb * 8); \
            GL2LDS((Btptr) + (size_t)(bn + r) * (Kdim) + k0 + o, Bs + (size_t)cb * 8);\
        }                                                                     \
        __syncthreads();                                                      \
        _Pragma("unroll")                                                     \
        for (int kc = 0; kc < 2; ++kc) {                                      \
            bf16x8 af[4], bfr[4];                                             \
            _Pragma("unroll")                                                 \
            for (int t = 0; t < 4; ++t) {                                     \
                const int am = wm + t * 16 + col;                             \
                const int aj = kc * 4 + quad;                                 \
                af[t] = *(const bf16x8*)&As[(size_t)am * 64 + ((aj ^ (am & 7)) * 8)]; \
                const int bn2 = wn + t * 16 + col;                            \
                bfr[t] = *(const bf16x8*)&Bs[(size_t)bn2 * 64 + ((aj ^ (bn2 & 7)) * 8)]; \
            }                                                                 \
            _Pragma("unroll")                                                 \
            for (int mt = 0; mt < 4; ++mt)                                    \
                _Pragma("unroll")                                             \
                for (int nt = 0; nt < 4; ++nt)                                \
                    acc[mt][nt] = __builtin_amdgcn_mfma_f32_16x16x32_bf16(    \
                        af[mt], bfr[nt], acc[mt][nt], 0, 0, 0);               \
        }                                                                     \
        __syncthreads();                                                      \
    }

// ---------------------------------------------------------------------------
// qkv GEMM with fused head-major scatter epilogue (+q biases).
// ---------------------------------------------------------------------------
__global__ __launch_bounds__(256, 2) void gemm_qkv(
    const u16* __restrict__ A, const u16* __restrict__ Bt,
    const float* __restrict__ rwb, const float* __restrict__ rrb,
    u16* __restrict__ qrw_b, u16* __restrict__ qrr_b,
    u16* __restrict__ kb, u16* __restrict__ vbT)
{
    GEMM_BODY(A, Bt, DMODEL)
    #pragma unroll
    for (int mt = 0; mt < 4; ++mt) {
        const int row0 = bm + wm + mt * 16 + quad * 4;
        const int b = row0 >> 11;
        const int s0 = row0 & 2047;
        #pragma unroll
        for (int nt = 0; nt < 4; ++nt) {
            const int cn = bn + wn + nt * 16 + col;     // [0,3072)
            const int sec = cn >> 10;                   // wave-uniform per nt
            const int cc = cn & 1023;
            const int h = cc >> 6, d = cc & 63;
            const int bh = b * NHEAD + h;
            if (sec == 0) {
                const float bw = rwb[cc], br = rrb[cc];
                #pragma unroll
                for (int r = 0; r < 4; ++r) {
                    const size_t o = ((size_t)bh * S_LEN + s0 + r) * 64 + d;
                    qrw_b[o] = (u16)f2bs(acc[mt][nt][r] + bw);
                    qrr_b[o] = (u16)f2bs(acc[mt][nt][r] + br);
                }
            } else if (sec == 1) {
                #pragma unroll
                for (int r = 0; r < 4; ++r)
                    kb[((size_t)bh * S_LEN + s0 + r) * 64 + d] =
                        (u16)f2bs(acc[mt][nt][r]);
            } else {
                short4v t;
                t[0] = f2bs(acc[mt][nt][0]); t[1] = f2bs(acc[mt][nt][1]);
                t[2] = f2bs(acc[mt][nt][2]); t[3] = f2bs(acc[mt][nt][3]);
                *(short4v*)(vbT + ((size_t)bh * 64 + d) * S_LEN + s0) = t;
            }
        }
    }
}

// ---------------------------------------------------------------------------
// rel GEMM with fused head-major scatter: rkb [NHEAD][S][64].
// ---------------------------------------------------------------------------
__global__ __launch_bounds__(256, 2) void gemm_rel(
    const u16* __restrict__ A, const u16* __restrict__ Bt,
    u16* __restrict__ rkb)
{
    GEMM_BODY(A, Bt, DMODEL)
    #pragma unroll
    for (int mt = 0; mt < 4; ++mt) {
        const int l0 = bm + wm + mt * 16 + quad * 4;
        #pragma unroll
        for (int nt = 0; nt < 4; ++nt) {
            const int cn = bn + wn + nt * 16 + col;
            const int h = cn >> 6, d = cn & 63;
            #pragma unroll
            for (int r = 0; r < 4; ++r)
                rkb[((size_t)h * S_LEN + l0 + r) * 64 + d] =
                    (u16)f2bs(acc[mt][nt][r]);
        }
    }
}

// ---------------------------------------------------------------------------
// Generic bf16 GEMM, fp32 output: C = A @ Bt^T (out-projection).
// ---------------------------------------------------------------------------
__global__ __launch_bounds__(256, 2) void gemm_out(
    const u16* __restrict__ A, const u16* __restrict__ Bt,
    float* __restrict__ Cf, int N, int K)
{
    GEMM_BODY(A, Bt, K)
    #pragma unroll
    for (int mt = 0; mt < 4; ++mt)
        #pragma unroll
        for (int nt = 0; nt < 4; ++nt)
            #pragma unroll
            for (int r = 0; r < 4; ++r) {
                const int row = bm + wm + mt * 16 + quad * 4 + r;
                const int cn = bn + wn + nt * 16 + col;
                Cf[(size_t)row * N + cn] = acc[mt][nt][r];
            }
}

// ---------------------------------------------------------------------------
// MFMA bf16 flash attention v6 = v4 structure (K/V/rk all LDS-staged,
// block-shared -- v5's per-wave V gather regressed 5x bank conflicts) plus:
//  - rotate-once diagonal extraction (20 bpermutes/step, was 32)
//  - wave-uniform select specialization: full 3-way region merge only on the
//    single mixed step per wave; dw==-16 needs one zeroed column; the other
//    ~30/32 steps skip the merge entirely (dw multiple of 16, steps by -64).
// ---------------------------------------------------------------------------
__global__ __launch_bounds__(512, 2) void flash_attn(
    const u16* __restrict__ qrw_b, const u16* __restrict__ qrr_b,
    const u16* __restrict__ kb, const u16* __restrict__ vbT,
    const u16* __restrict__ rkb, const int* __restrict__ mask,
    u16* __restrict__ ctxb)
{
    const int lane = threadIdx.x & 63;
    const int w    = threadIdx.x >> 6;      // 0..7
    const int quad = lane >> 4;
    const int col  = lane & 15;
    const int bh   = blockIdx.y;
    const int b    = bh >> 4;
    const int n    = bh & 15;
    const int B0   = blockIdx.x * 128;
    const int iw0  = B0 + w * 16;

    __shared__ u16 Ks[64 * 64];      // XOR-swizzled
    __shared__ u16 Vs[64 * 64];
    __shared__ u16 Rs[192 * 64];     // rk panel
    __shared__ u16 Pr[8][16][72];
    __shared__ float madd[S_LEN];

    const size_t headQ = (size_t)bh * S_LEN * 64;
    const size_t headR = (size_t)n  * S_LEN * 64;

    for (int i = threadIdx.x; i < S_LEN; i += 512)
        madd[i] = mask[b * S_LEN + i] ? -16384.f : 0.f;

    bf16x8 a_rw[2], a_rr0[2], a_rr1[2];
    {
        const int r0 = iw0 + col;
        const int r1 = (r0 + 1 < S_LEN) ? (r0 + 1) : (S_LEN - 1);
        #pragma unroll
        for (int kc = 0; kc < 2; ++kc) {
            const int doff = kc * 32 + quad * 8;
            a_rw[kc]  = *(const bf16x8*)(qrw_b + headQ + (size_t)r0 * 64 + doff);
            a_rr0[kc] = *(const bf16x8*)(qrr_b + headQ + (size_t)r0 * 64 + doff);
            a_rr1[kc] = *(const bf16x8*)(qrr_b + headQ + (size_t)r1 * 64 + doff);
        }
    }

    f32x4 O[4];
    float l_acc[4] = {0.f, 0.f, 0.f, 0.f};
    #pragma unroll
    for (int dt = 0; dt < 4; ++dt) O[dt] = (f32x4){0.f, 0.f, 0.f, 0.f};

    const int swz  = ((lane & 7) ^ ((lane >> 3) & 7)) * 8;
    const int lrow = lane >> 3;
    const int csel = col & 7;

    for (int u0 = 0; u0 < S_LEN; u0 += 64) {
        const int dblk = B0 - u0;                 // block-uniform, mult of 64
        const int dw = dblk + 16 * w;             // wave-uniform
        const bool mixed = (dw >= 0) && (dw <= 48);
        __syncthreads();
        // ---- stage K (8 chunks), V (8), rk panel (24); 5 chunks/wave ----
        const int pbase = (dblk >= 0) ? (S_LEN - 128 - dblk) : (-dblk - 129);
        #pragma unroll
        for (int t = 0; t < 5; ++t) {
            const int idx = w * 5 + t;
            if (idx < 8) {
                GL2LDS(kb + headQ + (size_t)(u0 + idx * 8 + lrow) * 64 + swz,
                       Ks + idx * 512);
            } else if (idx < 16) {
                const int c = idx - 8;
                GL2LDS(vbT + ((size_t)bh * 64 + c * 8 + lrow) * S_LEN + u0 + swz,
                       Vs + c * 512);
            } else {
                const int c = idx - 16;
                int rr = pbase + c * 8 + lrow;
                rr = rr < 0 ? 0 : (rr > S_LEN - 1 ? S_LEN - 1 : rr);
                GL2LDS(rkb + headR + (size_t)rr * 64 + swz, Rs + c * 512);
            }
        }
        // mixed waves only: direct-VGPR loads of the other region
        bf16x8 rf2[5][2];
        if (mixed) {
            #pragma unroll
            for (int g = 0; g < 5; ++g) {
                const int u = g * 16 + col;
                int row = (dblk >= 0) ? (u - dw - 17) : (S_LEN - 16 - dw + u);
                row = row < 0 ? 0 : (row > S_LEN - 1 ? S_LEN - 1 : row);
                const u16* rb = rkb + headR + (size_t)row * 64 + quad * 8;
                rf2[g][0] = *(const bf16x8*)(rb);
                rf2[g][1] = *(const bf16x8*)(rb + 32);
            }
        }
        __syncthreads();

        // ---- ac = Qrw . K^T ----
        f32x4 sc[4];
        #pragma unroll
        for (int nt = 0; nt < 4; ++nt) {
            const int m = nt * 16 + col;
            bf16x8 k0 = *(const bf16x8*)&Ks[m * 64 + ((quad ^ csel) * 8)];
            bf16x8 k1 = *(const bf16x8*)&Ks[m * 64 + (((4 + quad) ^ csel) * 8)];
            f32x4 c = (f32x4){0.f, 0.f, 0.f, 0.f};
            c = __builtin_amdgcn_mfma_f32_16x16x32_bf16(a_rw[0], k0, c, 0, 0, 0);
            c = __builtin_amdgcn_mfma_f32_16x16x32_bf16(a_rw[1], k1, c, 0, 0, 0);
            sc[nt] = c;
        }

        // ---- bd: panel GEMM ----
        f32x4 pnl[5];
        {
            const bf16x8* aP = (dblk >= 0) ? a_rr0 : a_rr1;
            #pragma unroll
            for (int g = 0; g < 5; ++g) {
                const int m = g * 16 + col + 112 - 16 * w;   // m&7 == col&7
                bf16x8 r0 = *(const bf16x8*)&Rs[m * 64 + ((quad ^ csel) * 8)];
                bf16x8 r1 = *(const bf16x8*)&Rs[m * 64 + (((4 + quad) ^ csel) * 8)];
                f32x4 c = (f32x4){0.f, 0.f, 0.f, 0.f};
                c = __builtin_amdgcn_mfma_f32_16x16x32_bf16(aP[0], r0, c, 0, 0, 0);
                c = __builtin_amdgcn_mfma_f32_16x16x32_bf16(aP[1], r1, c, 0, 0, 0);
                pnl[g] = c;
            }
        }
        if (mixed) {
            // other-region GEMM + full 3-way select (one step per wave)
            const bf16x8* aV = (dblk >= 0) ? a_rr1 : a_rr0;
            const int lim1 = 15 + dw;
            #pragma unroll
            for (int g = 0; g < 5; ++g) {
                f32x4 c = (f32x4){0.f, 0.f, 0.f, 0.f};
                c = __builtin_amdgcn_mfma_f32_16x16x32_bf16(aV[0], rf2[g][0], c, 0, 0, 0);
                c = __builtin_amdgcn_mfma_f32_16x16x32_bf16(aV[1], rf2[g][1], c, 0, 0, 0);
                const int u = g * 16 + col;
                #pragma unroll
                for (int r = 0; r < 4; ++r) {
                    const float r1v = (dblk >= 0) ? pnl[g][r] : c[r];
                    const float r2v = (dblk >= 0) ? c[r] : pnl[g][r];
                    pnl[g][r] = (u <= lim1) ? r1v : ((u == lim1 + 1) ? 0.f : r2v);
                }
            }
        } else if (dw == -16) {
            // zero column u==0 (the rel-shift zero diag enters this step once)
            if (col == 0) {
                #pragma unroll
                for (int r = 0; r < 4; ++r) pnl[0][r] = 0.f;
            }
        }
        // all other steps: panel result is exact, no merge needed.

        // ---- extract diagonal (rotate-once-per-r), exp, accumulate l ----
        float madd_v[4];
        #pragma unroll
        for (int nt = 0; nt < 4; ++nt)
            madd_v[nt] = madd[u0 + nt * 16 + col];
        #pragma unroll
        for (int r = 0; r < 4; ++r) {
            const int uo = col + 15 - quad * 4 - r;       // [0,30]
            const int src = (quad << 4) | (uo & 15);
            float rot[5];
            #pragma unroll
            for (int g = 0; g < 5; ++g)
                rot[g] = __shfl(pnl[g][r], src, 64);
            #pragma unroll
            for (int nt = 0; nt < 4; ++nt) {
                const float bd = (uo < 16) ? rot[nt] : rot[nt + 1];
                const float p = __expf(fmaf(sc[nt][r] + bd, 0.125f, madd_v[nt]));
                sc[nt][r] = p;
                l_acc[r] += p;
            }
        }

        // ---- P: C-layout -> LDS row-major -> A-frags ----
        #pragma unroll
        for (int nt = 0; nt < 4; ++nt)
            #pragma unroll
            for (int r = 0; r < 4; ++r)
                Pr[w][quad * 4 + r][nt * 16 + col] = (u16)f2bs(sc[nt][r]);
        bf16x8 pa[2];
        pa[0] = *(const bf16x8*)&Pr[w][col][quad * 8];
        pa[1] = *(const bf16x8*)&Pr[w][col][32 + quad * 8];

        // ---- O += P . V ----
        #pragma unroll
        for (int dt = 0; dt < 4; ++dt) {
            const int m = dt * 16 + col;
            bf16x8 v0 = *(const bf16x8*)&Vs[m * 64 + ((quad ^ csel) * 8)];
            bf16x8 v1 = *(const bf16x8*)&Vs[m * 64 + (((4 + quad) ^ csel) * 8)];
            f32x4 c = O[dt];
            c = __builtin_amdgcn_mfma_f32_16x16x32_bf16(pa[0], v0, c, 0, 0, 0);
            c = __builtin_amdgcn_mfma_f32_16x16x32_bf16(pa[1], v1, c, 0, 0, 0);
            O[dt] = c;
        }
    }

    float inv[4];
    #pragma unroll
    for (int r = 0; r < 4; ++r) {
        float s = l_acc[r];
        #pragma unroll
        for (int off = 1; off < 16; off <<= 1)
            s += __shfl_xor(s, off, 64);
        inv[r] = 1.f / s;
    }
    #pragma unroll
    for (int dt = 0; dt < 4; ++dt)
        #pragma unroll
        for (int r = 0; r < 4; ++r) {
            const int i = iw0 + quad * 4 + r;
            ctxb[((size_t)b * S_LEN + i) * DMODEL + n * 64 + dt * 16 + col] =
                (u16)f2bs(O[dt][r] * inv[r]);
        }
}

// ---------------------------------------------------------------------------
// out = LayerNorm(x + attn_out)
// ---------------------------------------------------------------------------
__global__ __launch_bounds__(256) void ln_kernel(const float* __restrict__ x,
                                                 const float* __restrict__ ao,
                                                 const float* __restrict__ gamma,
                                                 const float* __restrict__ beta,
                                                 float* __restrict__ out) {
    const int r = blockIdx.x;
    const int tid = threadIdx.x;
    const size_t base = (size_t)r * DMODEL + tid * 4;
    float4 xv = *(const float4*)(x + base);
    float4 av = *(const float4*)(ao + base);
    float v0 = xv.x + av.x, v1 = xv.y + av.y, v2 = xv.z + av.z, v3 = xv.w + av.w;

    float s = v0 + v1 + v2 + v3;
    #pragma unroll
    for (int off = 32; off > 0; off >>= 1) s += __shfl_xor(s, off, 64);
    __shared__ float red[4];
    __shared__ float red2[4];
    if ((tid & 63) == 0) red[tid >> 6] = s;
    __syncthreads();
    float mu = (red[0] + red[1] + red[2] + red[3]) * (1.0f / DMODEL);

    float d0 = v0 - mu, d1 = v1 - mu, d2 = v2 - mu, d3 = v3 - mu;
    float q = d0 * d0 + d1 * d1 + d2 * d2 + d3 * d3;
    #pragma unroll
    for (int off = 32; off > 0; off >>= 1) q += __shfl_xor(q, off, 64);
    if ((tid & 63) == 0) red2[tid >> 6] = q;
    __syncthreads();
    float var = (red2[0] + red2[1] + red2[2] + red2[3]) * (1.0f / DMODEL);
    float rstd = rsqrtf(var + 1e-5f);

    float4 g  = *(const float4*)(gamma + tid * 4);
    float4 be = *(const float4*)(beta + tid * 4);
    float4 o = make_float4(d0 * rstd * g.x + be.x,
                           d1 * rstd * g.y + be.y,
                           d2 * rstd * g.z + be.z,
                           d3 * rstd * g.w + be.w);
    *(float4*)(out + base) = o;
}

// ---------------------------------------------------------------------------
extern "C" void kernel_launch(void* const* d_in, const int* in_sizes, int n_in,
                              void* d_out, int out_size, void* d_ws, size_t ws_size,
                              hipStream_t stream) {
    const float* x    = (const float*)d_in[0];
    const float* rpos = (const float*)d_in[1];
    const float* rwb  = (const float*)d_in[2];
    const float* rrb  = (const float*)d_in[3];
    const int*   mask = (const int*)  d_in[4];
    const float* Wqkv = (const float*)d_in[5];
    const float* Wrel = (const float*)d_in[6];
    const float* Wout = (const float*)d_in[7];
    const float* gam  = (const float*)d_in[8];
    const float* bet  = (const float*)d_in[9];
    float* out = (float*)d_out;

    // ---- workspace layout (u16 units), ~86 MB ----
    u16* wsb   = (u16*)d_ws;
    u16* ctxb  = wsb;                        // [4096][1024] bf16
    float* ao  = (float*)(wsb + 4194304);    // [4096][1024] f32
    u16* qrw_b = wsb + 12582912;             // [BH][S][64]
    u16* qrr_b = qrw_b + 4194304;
    u16* kb    = qrr_b + 4194304;
    u16* vbT   = kb + 4194304;               // [BH][64][S]
    u16* rkb   = vbT + 4194304;              // [NHEAD][S][64]
    u16* xb    = rkb + 2097152;              // [4096][1024]
    u16* rposb = xb + 4194304;               // [2048][1024]
    u16* Wqkvt = rposb + 2097152;            // [3072][1024]
    u16* Wrelt = Wqkvt + 3145728;            // [1024][1024]
    u16* Woutt = Wrelt + 1048576;            // [1024][1024]

    dim3 blk(256);
    cast_all<<<dim3(6144), blk, 0, stream>>>(x, rpos, xb, rposb);
    transp_cast_all<<<dim3(80, 16), blk, 0, stream>>>(Wqkv, Wrel, Wout,
                                                      Wqkvt, Wrelt, Woutt);
    gemm_qkv<<<dim3(24, 32), blk, 0, stream>>>(xb, Wqkvt, rwb, rrb,
                                               qrw_b, qrr_b, kb, vbT);
    gemm_rel<<<dim3(8, 16), blk, 0, stream>>>(rposb, Wrelt, rkb);
    flash_attn<<<dim3(S_LEN / 128, NBATCH * NHEAD), dim3(512), 0, stream>>>(
        qrw_b, qrr_b, kb, vbT, rkb, mask, ctxb);
    gemm_out<<<dim3(8, 32), blk, 0, stream>>>(ctxb, Woutt, ao, DMODEL, DMODEL);
    ln_kernel<<<dim3(NBATCH * S_LEN), blk, 0, stream>>>(x, ao, gam, bet, out);
}

// Round 8
// 337.610 us; speedup vs baseline: 1.3736x; 1.2368x over previous
//
#include <hip/hip_runtime.h>
#include <hip/hip_bf16.h>
#include <math.h>

#define S_LEN 2048
#define NHEAD 16
#define DHEAD 64
#define DMODEL 1024
#define NBATCH 2

typedef unsigned short u16;
typedef __attribute__((ext_vector_type(8))) short bf16x8;
typedef __attribute__((ext_vector_type(4))) short short4v;
typedef __attribute__((ext_vector_type(4))) float f32x4;

__device__ __forceinline__ short f2bs(float x) {
    __hip_bfloat16 h = __float2bfloat16(x);
    return __builtin_bit_cast(short, h);
}

#define GL2LDS(g, l)                                                         \
    __builtin_amdgcn_global_load_lds(                                        \
        (const __attribute__((address_space(1))) void*)(g),                  \
        (__attribute__((address_space(3))) void*)(l), 16, 0, 0)

// ---------------------------------------------------------------------------
// fused fp32 -> bf16 casts: x (4096 blocks) then rpos (2048 blocks).
// ---------------------------------------------------------------------------
__global__ __launch_bounds__(256) void cast_all(const float* __restrict__ x,
                                                const float* __restrict__ rpos,
                                                u16* __restrict__ xb,
                                                u16* __restrict__ rposb) {
    int bid = blockIdx.x;
    const float* in;
    u16* out;
    if (bid < 4096) { in = x; out = xb; }
    else            { in = rpos; out = rposb; bid -= 4096; }
    const int i = (bid * 256 + threadIdx.x) * 4;
    float4 v = *(const float4*)(in + i);
    short4v t;
    t[0] = f2bs(v.x); t[1] = f2bs(v.y); t[2] = f2bs(v.z); t[3] = f2bs(v.w);
    *(short4v*)(out + i) = t;
}

// ---------------------------------------------------------------------------
// fused W [K][N] fp32 -> Wt [N][K] bf16 for Wqkv / Wrel / Wout.
// grid (80, 16): bx<48 -> Wqkv, <64 -> Wrel, else Wout. K=1024 for all.
// ---------------------------------------------------------------------------
__global__ __launch_bounds__(256) void transp_cast_all(
    const float* __restrict__ Wqkv, const float* __restrict__ Wrel,
    const float* __restrict__ Wout,
    u16* __restrict__ Wqkvt, u16* __restrict__ Wrelt, u16* __restrict__ Woutt)
{
    __shared__ float t[64][65];
    int bx = blockIdx.x;
    const float* W;
    u16* Wt;
    int N;
    if (bx < 48)      { W = Wqkv; Wt = Wqkvt; N = 3 * DMODEL; }
    else if (bx < 64) { W = Wrel; Wt = Wrelt; N = DMODEL; bx -= 48; }
    else              { W = Wout; Wt = Woutt; N = DMODEL; bx -= 64; }
    const int k0 = blockIdx.y * 64, n0 = bx * 64;
    const int r = threadIdx.x >> 4;
    const int c4 = (threadIdx.x & 15) * 4;
    #pragma unroll
    for (int it = 0; it < 4; ++it) {
        float4 v = *(const float4*)(W + (size_t)(k0 + it * 16 + r) * N + n0 + c4);
        t[c4 + 0][it * 16 + r] = v.x;
        t[c4 + 1][it * 16 + r] = v.y;
        t[c4 + 2][it * 16 + r] = v.z;
        t[c4 + 3][it * 16 + r] = v.w;
    }
    __syncthreads();
    #pragma unroll
    for (int it = 0; it < 4; ++it) {
        const int nn = it * 16 + r;
        short4v o;
        o[0] = f2bs(t[nn][c4 + 0]); o[1] = f2bs(t[nn][c4 + 1]);
        o[2] = f2bs(t[nn][c4 + 2]); o[3] = f2bs(t[nn][c4 + 3]);
        *(short4v*)(Wt + (size_t)(n0 + nn) * DMODEL + k0 + c4) = o;
    }
}

// ---------------------------------------------------------------------------
// Shared GEMM main-loop macro: 128x128 tile, BK=64, XOR-swizzled LDS,
// global_load_lds width-16. Leaves acc[4][4] (f32x4) computed.
// ---------------------------------------------------------------------------
#define GEMM_BODY(Aptr, Btptr, Kdim)                                          \
    __shared__ u16 As[128 * 64];                                              \
    __shared__ u16 Bs[128 * 64];                                              \
    const int tid = threadIdx.x;                                              \
    const int lane = tid & 63;                                                \
    const int w = tid >> 6;                                                   \
    const int quad = lane >> 4, col = lane & 15;                              \
    const int bm = blockIdx.y * 128, bn = blockIdx.x * 128;                   \
    const int wm = (w >> 1) * 64, wn = (w & 1) * 64;                          \
    f32x4 acc[4][4];                                                          \
    _Pragma("unroll")                                                         \
    for (int mt = 0; mt < 4; ++mt)                                            \
        _Pragma("unroll")                                                     \
        for (int nt = 0; nt < 4; ++nt) acc[mt][nt] = (f32x4){0.f,0.f,0.f,0.f};\
    for (int k0 = 0; k0 < (Kdim); k0 += 64) {                                 \
        _Pragma("unroll")                                                     \
        for (int it = 0; it < 4; ++it) {                                      \
            const int cb = it * 256 + w * 64;                                 \
            const int c = cb + lane;                                          \
            const int r = c >> 3;                                             \
            const int o = ((c & 7) ^ (r & 7)) * 8;                            \
            GL2LDS((Aptr) + (size_t)(bm + r) * (Kdim) + k0 + o, As + (size_t)cb * 8); \
            GL2LDS((Btptr) + (size_t)(bn + r) * (Kdim) + k0 + o, Bs + (size_t)cb * 8);\
        }                                                                     \
        __syncthreads();                                                      \
        _Pragma("unroll")                                                     \
        for (int kc = 0; kc < 2; ++kc) {                                      \
            bf16x8 af[4], bfr[4];                                             \
            _Pragma("unroll")                                                 \
            for (int t = 0; t < 4; ++t) {                                     \
                const int am = wm + t * 16 + col;                             \
                const int aj = kc * 4 + quad;                                 \
                af[t] = *(const bf16x8*)&As[(size_t)am * 64 + ((aj ^ (am & 7)) * 8)]; \
                const int bn2 = wn + t * 16 + col;                            \
                bfr[t] = *(const bf16x8*)&Bs[(size_t)bn2 * 64 + ((aj ^ (bn2 & 7)) * 8)]; \
            }                                                                 \
            _Pragma("unroll")                                                 \
            for (int mt = 0; mt < 4; ++mt)                                    \
                _Pragma("unroll")                                             \
                for (int nt = 0; nt < 4; ++nt)                                \
                    acc[mt][nt] = __builtin_amdgcn_mfma_f32_16x16x32_bf16(    \
                        af[mt], bfr[nt], acc[mt][nt], 0, 0, 0);               \
        }                                                                     \
        __syncthreads();                                                      \
    }

// ---------------------------------------------------------------------------
// qkv GEMM with fused head-major scatter epilogue (+q biases).
// ---------------------------------------------------------------------------
__global__ __launch_bounds__(256, 2) void gemm_qkv(
    const u16* __restrict__ A, const u16* __restrict__ Bt,
    const float* __restrict__ rwb, const float* __restrict__ rrb,
    u16* __restrict__ qrw_b, u16* __restrict__ qrr_b,
    u16* __restrict__ kb, u16* __restrict__ vbT)
{
    GEMM_BODY(A, Bt, DMODEL)
    #pragma unroll
    for (int mt = 0; mt < 4; ++mt) {
        const int row0 = bm + wm + mt * 16 + quad * 4;
        const int b = row0 >> 11;
        const int s0 = row0 & 2047;
        #pragma unroll
        for (int nt = 0; nt < 4; ++nt) {
            const int cn = bn + wn + nt * 16 + col;     // [0,3072)
            const int sec = cn >> 10;                   // wave-uniform per nt
            const int cc = cn & 1023;
            const int h = cc >> 6, d = cc & 63;
            const int bh = b * NHEAD + h;
            if (sec == 0) {
                const float bw = rwb[cc], br = rrb[cc];
                #pragma unroll
                for (int r = 0; r < 4; ++r) {
                    const size_t o = ((size_t)bh * S_LEN + s0 + r) * 64 + d;
                    qrw_b[o] = (u16)f2bs(acc[mt][nt][r] + bw);
                    qrr_b[o] = (u16)f2bs(acc[mt][nt][r] + br);
                }
            } else if (sec == 1) {
                #pragma unroll
                for (int r = 0; r < 4; ++r)
                    kb[((size_t)bh * S_LEN + s0 + r) * 64 + d] =
                        (u16)f2bs(acc[mt][nt][r]);
            } else {
                short4v t;
                t[0] = f2bs(acc[mt][nt][0]); t[1] = f2bs(acc[mt][nt][1]);
                t[2] = f2bs(acc[mt][nt][2]); t[3] = f2bs(acc[mt][nt][3]);
                *(short4v*)(vbT + ((size_t)bh * 64 + d) * S_LEN + s0) = t;
            }
        }
    }
}

// ---------------------------------------------------------------------------
// rel GEMM with fused head-major scatter: rkb [NHEAD][S][64].
// ---------------------------------------------------------------------------
__global__ __launch_bounds__(256, 2) void gemm_rel(
    const u16* __restrict__ A, const u16* __restrict__ Bt,
    u16* __restrict__ rkb)
{
    GEMM_BODY(A, Bt, DMODEL)
    #pragma unroll
    for (int mt = 0; mt < 4; ++mt) {
        const int l0 = bm + wm + mt * 16 + quad * 4;
        #pragma unroll
        for (int nt = 0; nt < 4; ++nt) {
            const int cn = bn + wn + nt * 16 + col;
            const int h = cn >> 6, d = cn & 63;
            #pragma unroll
            for (int r = 0; r < 4; ++r)
                rkb[((size_t)h * S_LEN + l0 + r) * 64 + d] =
                    (u16)f2bs(acc[mt][nt][r]);
        }
    }
}

// ---------------------------------------------------------------------------
// Generic bf16 GEMM, fp32 output: C = A @ Bt^T (out-projection).
// ---------------------------------------------------------------------------
__global__ __launch_bounds__(256, 2) void gemm_out(
    const u16* __restrict__ A, const u16* __restrict__ Bt,
    float* __restrict__ Cf, int N, int K)
{
    GEMM_BODY(A, Bt, K)
    #pragma unroll
    for (int mt = 0; mt < 4; ++mt)
        #pragma unroll
        for (int nt = 0; nt < 4; ++nt)
            #pragma unroll
            for (int r = 0; r < 4; ++r) {
                const int row = bm + wm + mt * 16 + quad * 4 + r;
                const int cn = bn + wn + nt * 16 + col;
                Cf[(size_t)row * N + cn] = acc[mt][nt][r];
            }
}

// ---------------------------------------------------------------------------
// MFMA bf16 flash attention v7 = round-5 champion (172.6 us) VERBATIM except
// one change: ROLLING rk panel. The panel base advances +64/step within each
// region phase, so Rs becomes a 3x64-row circular buffer (roff in {0,64,128}).
// Full 192-row restage only at u0==0 and the region boundary (dblk==-64);
// all other steps stage just 8 new chunks. Staged bytes/step: 40KB -> 24KB.
// Swizzle key preserved: slot = (m+roff)%192, roff%8==0 -> slot&7 == col&7.
// (r6/r7's extraction/select restructures regressed 5x bank conflicts and
//  are NOT carried; r5's 32-shfl extraction + every-step select restored.)
// ---------------------------------------------------------------------------
__global__ __launch_bounds__(512, 2) void flash_attn(
    const u16* __restrict__ qrw_b, const u16* __restrict__ qrr_b,
    const u16* __restrict__ kb, const u16* __restrict__ vbT,
    const u16* __restrict__ rkb, const int* __restrict__ mask,
    u16* __restrict__ ctxb)
{
    const int lane = threadIdx.x & 63;
    const int w    = threadIdx.x >> 6;      // 0..7
    const int quad = lane >> 4;
    const int col  = lane & 15;
    const int bh   = blockIdx.y;
    const int b    = bh >> 4;
    const int n    = bh & 15;
    const int B0   = blockIdx.x * 128;
    const int iw0  = B0 + w * 16;

    __shared__ u16 Ks[64 * 64];      // XOR-swizzled
    __shared__ u16 Vs[64 * 64];
    __shared__ u16 Rs[192 * 64];     // rk panel (circular, 3 x 64 rows)
    __shared__ u16 Pr[8][16][72];
    __shared__ float madd[S_LEN];

    const size_t headQ = (size_t)bh * S_LEN * 64;
    const size_t headR = (size_t)n  * S_LEN * 64;

    for (int i = threadIdx.x; i < S_LEN; i += 512)
        madd[i] = mask[b * S_LEN + i] ? -16384.f : 0.f;

    bf16x8 a_rw[2], a_rr0[2], a_rr1[2];
    {
        const int r0 = iw0 + col;
        const int r1 = (r0 + 1 < S_LEN) ? (r0 + 1) : (S_LEN - 1);
        #pragma unroll
        for (int kc = 0; kc < 2; ++kc) {
            const int doff = kc * 32 + quad * 8;
            a_rw[kc]  = *(const bf16x8*)(qrw_b + headQ + (size_t)r0 * 64 + doff);
            a_rr0[kc] = *(const bf16x8*)(qrr_b + headQ + (size_t)r0 * 64 + doff);
            a_rr1[kc] = *(const bf16x8*)(qrr_b + headQ + (size_t)r1 * 64 + doff);
        }
    }

    f32x4 O[4];
    float l_acc[4] = {0.f, 0.f, 0.f, 0.f};
    #pragma unroll
    for (int dt = 0; dt < 4; ++dt) O[dt] = (f32x4){0.f, 0.f, 0.f, 0.f};

    const int swz  = ((lane & 7) ^ ((lane >> 3) & 7)) * 8;
    const int lrow = lane >> 3;
    const int csel = col & 7;
    int roff = 0;

    for (int u0 = 0; u0 < S_LEN; u0 += 64) {
        const int dblk = B0 - u0;                 // block-uniform, mult of 64
        const int dw = dblk + 16 * w;             // wave-uniform
        const bool mixed = (dw >= 0) && (dw <= 48);
        const bool full = (u0 == 0) || (dblk == -64);   // phase starts
        const int pbase = (dblk >= 0) ? (S_LEN - 128 - dblk) : (-dblk - 129);
        __syncthreads();
        if (full) {
            roff = 0;
            // ---- stage K (8 chunks), V (8), rk panel (24); 5/wave ----
            #pragma unroll
            for (int t = 0; t < 5; ++t) {
                const int idx = w * 5 + t;
                if (idx < 8) {
                    GL2LDS(kb + headQ + (size_t)(u0 + idx * 8 + lrow) * 64 + swz,
                           Ks + idx * 512);
                } else if (idx < 16) {
                    const int c = idx - 8;
                    GL2LDS(vbT + ((size_t)bh * 64 + c * 8 + lrow) * S_LEN + u0 + swz,
                           Vs + c * 512);
                } else {
                    const int c = idx - 16;
                    int rr = pbase + c * 8 + lrow;
                    rr = rr < 0 ? 0 : (rr > S_LEN - 1 ? S_LEN - 1 : rr);
                    GL2LDS(rkb + headR + (size_t)rr * 64 + swz, Rs + c * 512);
                }
            }
        } else {
            const int old_roff = roff;
            roff += 64; if (roff >= 192) roff -= 192;
            // ---- stage K (8), V (8), new rk rows (8); 3/wave ----
            #pragma unroll
            for (int t = 0; t < 3; ++t) {
                const int idx = w * 3 + t;
                if (idx < 8) {
                    GL2LDS(kb + headQ + (size_t)(u0 + idx * 8 + lrow) * 64 + swz,
                           Ks + idx * 512);
                } else if (idx < 16) {
                    const int c = idx - 8;
                    GL2LDS(vbT + ((size_t)bh * 64 + c * 8 + lrow) * S_LEN + u0 + swz,
                           Vs + c * 512);
                } else {
                    const int c = idx - 16;             // 0..7
                    int rr = pbase + 128 + c * 8 + lrow;
                    rr = rr < 0 ? 0 : (rr > S_LEN - 1 ? S_LEN - 1 : rr);
                    GL2LDS(rkb + headR + (size_t)rr * 64 + swz,
                           Rs + (size_t)(old_roff + c * 8) * 64);
                }
            }
        }
        // mixed waves: direct-VGPR loads of the other region
        bf16x8 rf2[5][2];
        if (mixed) {
            #pragma unroll
            for (int g = 0; g < 5; ++g) {
                const int u = g * 16 + col;
                int row = (dblk >= 0) ? (u - dw - 17) : (S_LEN - 16 - dw + u);
                row = row < 0 ? 0 : (row > S_LEN - 1 ? S_LEN - 1 : row);
                const u16* rb = rkb + headR + (size_t)row * 64 + quad * 8;
                rf2[g][0] = *(const bf16x8*)(rb);
                rf2[g][1] = *(const bf16x8*)(rb + 32);
            }
        }
        __syncthreads();

        // ---- ac = Qrw . K^T ----
        f32x4 sc[4];
        #pragma unroll
        for (int nt = 0; nt < 4; ++nt) {
            const int m = nt * 16 + col;
            bf16x8 k0 = *(const bf16x8*)&Ks[m * 64 + ((quad ^ csel) * 8)];
            bf16x8 k1 = *(const bf16x8*)&Ks[m * 64 + (((4 + quad) ^ csel) * 8)];
            f32x4 c = (f32x4){0.f, 0.f, 0.f, 0.f};
            c = __builtin_amdgcn_mfma_f32_16x16x32_bf16(a_rw[0], k0, c, 0, 0, 0);
            c = __builtin_amdgcn_mfma_f32_16x16x32_bf16(a_rw[1], k1, c, 0, 0, 0);
            sc[nt] = c;
        }

        // ---- bd: panel GEMM (+ VGPR pass for mixed waves) ----
        f32x4 pnl[5], oth[5];
        {
            const bf16x8* aP = (dblk >= 0) ? a_rr0 : a_rr1;
            #pragma unroll
            for (int g = 0; g < 5; ++g) {
                const int m = g * 16 + col + 112 - 16 * w;   // m&7 == col&7
                int slot = m + roff; if (slot >= 192) slot -= 192;
                bf16x8 r0 = *(const bf16x8*)&Rs[slot * 64 + ((quad ^ csel) * 8)];
                bf16x8 r1 = *(const bf16x8*)&Rs[slot * 64 + (((4 + quad) ^ csel) * 8)];
                f32x4 c = (f32x4){0.f, 0.f, 0.f, 0.f};
                c = __builtin_amdgcn_mfma_f32_16x16x32_bf16(aP[0], r0, c, 0, 0, 0);
                c = __builtin_amdgcn_mfma_f32_16x16x32_bf16(aP[1], r1, c, 0, 0, 0);
                pnl[g] = c;
            }
        }
        #pragma unroll
        for (int g = 0; g < 5; ++g) oth[g] = (f32x4){0.f, 0.f, 0.f, 0.f};
        if (mixed) {
            const bf16x8* aV = (dblk >= 0) ? a_rr1 : a_rr0;
            #pragma unroll
            for (int g = 0; g < 5; ++g) {
                f32x4 c = (f32x4){0.f, 0.f, 0.f, 0.f};
                c = __builtin_amdgcn_mfma_f32_16x16x32_bf16(aV[0], rf2[g][0], c, 0, 0, 0);
                c = __builtin_amdgcn_mfma_f32_16x16x32_bf16(aV[1], rf2[g][1], c, 0, 0, 0);
                oth[g] = c;
            }
        }
        // unified 3-way select into pnl[]
        const int lim1 = 15 + dw;
        #pragma unroll
        for (int g = 0; g < 5; ++g) {
            const int u = g * 16 + col;
            #pragma unroll
            for (int r = 0; r < 4; ++r) {
                const float r1v = (dblk >= 0) ? pnl[g][r] : oth[g][r];
                const float r2v = (dblk >= 0) ? oth[g][r] : pnl[g][r];
                pnl[g][r] = (u <= lim1) ? r1v : ((u == lim1 + 1) ? 0.f : r2v);
            }
        }

        // ---- extract diagonal, add ac, scale, mask, exp, accumulate l ----
        #pragma unroll
        for (int nt = 0; nt < 4; ++nt) {
            const float ma = madd[u0 + nt * 16 + col];
            #pragma unroll
            for (int r = 0; r < 4; ++r) {
                const int uo = col + 15 - quad * 4 - r;      // [0,30]
                const int src = (quad << 4) | (uo & 15);
                float blo = __shfl(pnl[nt][r], src, 64);
                float bhi = __shfl(pnl[nt + 1][r], src, 64);
                float bd = (uo < 16) ? blo : bhi;
                float p = __expf(fmaf(sc[nt][r] + bd, 0.125f, ma));
                sc[nt][r] = p;
                l_acc[r] += p;
            }
        }

        // ---- P: C-layout -> LDS row-major -> A-frags ----
        #pragma unroll
        for (int nt = 0; nt < 4; ++nt)
            #pragma unroll
            for (int r = 0; r < 4; ++r)
                Pr[w][quad * 4 + r][nt * 16 + col] = (u16)f2bs(sc[nt][r]);
        bf16x8 pa[2];
        pa[0] = *(const bf16x8*)&Pr[w][col][quad * 8];
        pa[1] = *(const bf16x8*)&Pr[w][col][32 + quad * 8];

        // ---- O += P . V ----
        #pragma unroll
        for (int dt = 0; dt < 4; ++dt) {
            const int m = dt * 16 + col;
            bf16x8 v0 = *(const bf16x8*)&Vs[m * 64 + ((quad ^ csel) * 8)];
            bf16x8 v1 = *(const bf16x8*)&Vs[m * 64 + (((4 + quad) ^ csel) * 8)];
            f32x4 c = O[dt];
            c = __builtin_amdgcn_mfma_f32_16x16x32_bf16(pa[0], v0, c, 0, 0, 0);
            c = __builtin_amdgcn_mfma_f32_16x16x32_bf16(pa[1], v1, c, 0, 0, 0);
            O[dt] = c;
        }
    }

    float inv[4];
    #pragma unroll
    for (int r = 0; r < 4; ++r) {
        float s = l_acc[r];
        #pragma unroll
        for (int off = 1; off < 16; off <<= 1)
            s += __shfl_xor(s, off, 64);
        inv[r] = 1.f / s;
    }
    #pragma unroll
    for (int dt = 0; dt < 4; ++dt)
        #pragma unroll
        for (int r = 0; r < 4; ++r) {
            const int i = iw0 + quad * 4 + r;
            ctxb[((size_t)b * S_LEN + i) * DMODEL + n * 64 + dt * 16 + col] =
                (u16)f2bs(O[dt][r] * inv[r]);
        }
}

// ---------------------------------------------------------------------------
// out = LayerNorm(x + attn_out)
// ---------------------------------------------------------------------------
__global__ __launch_bounds__(256) void ln_kernel(const float* __restrict__ x,
                                                 const float* __restrict__ ao,
                                                 const float* __restrict__ gamma,
                                                 const float* __restrict__ beta,
                                                 float* __restrict__ out) {
    const int r = blockIdx.x;
    const int tid = threadIdx.x;
    const size_t base = (size_t)r * DMODEL + tid * 4;
    float4 xv = *(const float4*)(x + base);
    float4 av = *(const float4*)(ao + base);
    float v0 = xv.x + av.x, v1 = xv.y + av.y, v2 = xv.z + av.z, v3 = xv.w + av.w;

    float s = v0 + v1 + v2 + v3;
    #pragma unroll
    for (int off = 32; off > 0; off >>= 1) s += __shfl_xor(s, off, 64);
    __shared__ float red[4];
    __shared__ float red2[4];
    if ((tid & 63) == 0) red[tid >> 6] = s;
    __syncthreads();
    float mu = (red[0] + red[1] + red[2] + red[3]) * (1.0f / DMODEL);

    float d0 = v0 - mu, d1 = v1 - mu, d2 = v2 - mu, d3 = v3 - mu;
    float q = d0 * d0 + d1 * d1 + d2 * d2 + d3 * d3;
    #pragma unroll
    for (int off = 32; off > 0; off >>= 1) q += __shfl_xor(q, off, 64);
    if ((tid & 63) == 0) red2[tid >> 6] = q;
    __syncthreads();
    float var = (red2[0] + red2[1] + red2[2] + red2[3]) * (1.0f / DMODEL);
    float rstd = rsqrtf(var + 1e-5f);

    float4 g  = *(const float4*)(gamma + tid * 4);
    float4 be = *(const float4*)(beta + tid * 4);
    float4 o = make_float4(d0 * rstd * g.x + be.x,
                           d1 * rstd * g.y + be.y,
                           d2 * rstd * g.z + be.z,
                           d3 * rstd * g.w + be.w);
    *(float4*)(out + base) = o;
}

// ---------------------------------------------------------------------------
extern "C" void kernel_launch(void* const* d_in, const int* in_sizes, int n_in,
                              void* d_out, int out_size, void* d_ws, size_t ws_size,
                              hipStream_t stream) {
    const float* x    = (const float*)d_in[0];
    const float* rpos = (const float*)d_in[1];
    const float* rwb  = (const float*)d_in[2];
    const float* rrb  = (const float*)d_in[3];
    const int*   mask = (const int*)  d_in[4];
    const float* Wqkv = (const float*)d_in[5];
    const float* Wrel = (const float*)d_in[6];
    const float* Wout = (const float*)d_in[7];
    const float* gam  = (const float*)d_in[8];
    const float* bet  = (const float*)d_in[9];
    float* out = (float*)d_out;

    // ---- workspace layout (u16 units), ~86 MB ----
    u16* wsb   = (u16*)d_ws;
    u16* ctxb  = wsb;                        // [4096][1024] bf16
    float* ao  = (float*)(wsb + 4194304);    // [4096][1024] f32
    u16* qrw_b = wsb + 12582912;             // [BH][S][64]
    u16* qrr_b = qrw_b + 4194304;
    u16* kb    = qrr_b + 4194304;
    u16* vbT   = kb + 4194304;               // [BH][64][S]
    u16* rkb   = vbT + 4194304;              // [NHEAD][S][64]
    u16* xb    = rkb + 2097152;              // [4096][1024]
    u16* rposb = xb + 4194304;               // [2048][1024]
    u16* Wqkvt = rposb + 2097152;            // [3072][1024]
    u16* Wrelt = Wqkvt + 3145728;            // [1024][1024]
    u16* Woutt = Wrelt + 1048576;            // [1024][1024]

    dim3 blk(256);
    cast_all<<<dim3(6144), blk, 0, stream>>>(x, rpos, xb, rposb);
    transp_cast_all<<<dim3(80, 16), blk, 0, stream>>>(Wqkv, Wrel, Wout,
                                                      Wqkvt, Wrelt, Woutt);
    gemm_qkv<<<dim3(24, 32), blk, 0, stream>>>(xb, Wqkvt, rwb, rrb,
                                               qrw_b, qrr_b, kb, vbT);
    gemm_rel<<<dim3(8, 16), blk, 0, stream>>>(rposb, Wrelt, rkb);
    flash_attn<<<dim3(S_LEN / 128, NBATCH * NHEAD), dim3(512), 0, stream>>>(
        qrw_b, qrr_b, kb, vbT, rkb, mask, ctxb);
    gemm_out<<<dim3(8, 32), blk, 0, stream>>>(ctxb, Woutt, ao, DMODEL, DMODEL);
    ln_kernel<<<dim3(NBATCH * S_LEN), blk, 0, stream>>>(x, ao, gam, bet, out);
}